// Round 9
// baseline (110.673 us; speedup 1.0000x reference)
//
#include <hip/hip_runtime.h>

#define K_RBF   32
#define LUT_N   256           // points over [LUT_LO, LUT_HI]
#define LUT_LO  (-8.0f)
#define LUT_HI  (8.0f)
// h = 16/256 = 0.0625, inv_h = 16
#define LUT_INVH 16.0f

// Reference constants at float32 precision, exactly as jnp.float32(...)
#define DT_F      0.005f
#define M_INV_F   ((float)(1.0 / 95.452))
#define OFFST_F   (-3.2902f)
#define F_V_F     214.9261f
#define F_C_F     19.3607f

#if __has_builtin(__builtin_amdgcn_exp2f)
#define EXP2(x) __builtin_amdgcn_exp2f(x)
#else
#define EXP2(x) exp2f(x)
#endif

// Native clang vectors — accepted by __builtin_nontemporal_{load,store}.
typedef float vfloat4 __attribute__((ext_vector_type(4)));
typedef float vfloat2 __attribute__((ext_vector_type(2)));

// ---------------------------------------------------------------------------
// Single fused kernel (R7 structure = best so far, plus two tweaks):
//  * LUT stored as float2 {f(x_i), f(x_{i+1})} -> ONE ds_read_b64 per element
//    (R7/R8 did two scalar ds_read_b32 gathers; Gaussian-clustered indices
//    make those ~2-4-way bank-conflicted).
//  * Plain stores (NT dropped — harness fills reach 6.4 TB/s with plain
//    stores; everything is L3-resident, NT write-around can only hurt).
// Phase 0 (hidden, per block): scalar table F[257], then pair table G[256].
// Phase 1: grid-stride, 2 elements/thread-iter, all streams lane-unit-stride.
// Math (identical to explicit Taylor-RK4; y0 dead; yd==k1, k3==k2):
//   st1 = C6*k1*(6 - M_INV*(4h+DT)*(FVC+f')),  st0 = DT*x + C6*(4h+DT)*k1
// LUT interp error ~2e-2 in f-space x 5.2e-5 output sensitivity -> ~1e-6.
// ---------------------------------------------------------------------------
__launch_bounds__(256)
__global__ void rk4_rbf_kernel(const vfloat2* __restrict__ u2,
                               const vfloat4* __restrict__ states4,
                               const float*  __restrict__ centers,
                               const float*  __restrict__ log_sigmas,
                               const float*  __restrict__ wts,
                               const float*  __restrict__ bptr,
                               vfloat4* __restrict__ out4,
                               int n_pairs) {
    __shared__ float4 P[K_RBF];      // {A, B, E, w} per RBF
    __shared__ float  F[LUT_N + 1];  // f(x_i), scalar staging
    __shared__ float2 G[LUT_N];      // {f(x_i), f(x_{i+1})} pairs, 2 KB

    if (threadIdx.x < K_RBF) {
        const float LOG2E = 1.4426950408889634f;
        int k = threadIdx.x;
        float s  = __expf(log_sigmas[k]);
        float s2 = s * s;
        float c  = centers[k];
        P[k] = make_float4(-s2 * LOG2E, 2.0f * s2 * c * LOG2E,
                           -s2 * c * c * LOG2E, wts[k]);
    }
    __syncthreads();
    {   // one LUT point per thread; thread 0 also does point LUT_N
        const float H = (LUT_HI - LUT_LO) / (float)LUT_N;
        float bb = bptr[0];
        for (int pt = threadIdx.x; pt <= LUT_N; pt += blockDim.x) {
            float xg = LUT_LO + (float)pt * H;
            float fv = bb;
#pragma unroll
            for (int k = 0; k < K_RBF; ++k) {
                float4 p = P[k];
                fv = fmaf(p.w, EXP2(fmaf(fmaf(p.x, xg, p.y), xg, p.z)), fv);
            }
            F[pt] = fv;
        }
    }
    __syncthreads();
    G[threadIdx.x] = make_float2(F[threadIdx.x], F[threadIdx.x + 1]);
    __syncthreads();

    const float FVC = F_V_F + F_C_F;
    const float C6  = DT_F / 6.0f;
    const float C1  = 0.015f * M_INV_F;   // M_INV*(4h+DT)
    const float C2  = C6 * 0.015f;        // C6*(4h+DT)

    int stride = gridDim.x * blockDim.x;
    for (int i = blockIdx.x * blockDim.x + threadIdx.x; i < n_pairs; i += stride) {
        vfloat4 s  = __builtin_nontemporal_load(&states4[i]);  // y0a,y1a,y0b,y1b
        vfloat2 uu = __builtin_nontemporal_load(&u2[i]);

        float x[2]  = { s.y, s.w };     // y1 (y0 is dead)
        float uv[2] = { uu.x, uu.y };
        float o[4];
#pragma unroll
        for (int e = 0; e < 2; ++e) {
            float t   = (x[e] - LUT_LO) * LUT_INVH;
            t = fminf(fmaxf(t, 0.0f), (float)(LUT_N - 1) + 0.999f);
            int   idx = (int)t;
            float fr  = t - (float)idx;
            float2 L  = G[idx];                     // one ds_read_b64
            float df  = L.y - L.x;
            float f   = fmaf(fr, df, L.x);          // f(x) incl. b
            float fp  = df * LUT_INVH;              // f'(x)

            float k1 = (uv[e] - FVC * x[e] - (OFFST_F + f)) * M_INV_F;
            float g  = 6.0f - C1 * (FVC + fp);
            o[2 * e]     = fmaf(C2, k1, DT_F * x[e]);   // st0
            o[2 * e + 1] = C6 * k1 * g;                 // st1
        }

        out4[i] = vfloat4{ o[0], o[1], o[2], o[3] };    // plain store
    }
}

extern "C" void kernel_launch(void* const* d_in, const int* in_sizes, int n_in,
                              void* d_out, int out_size, void* d_ws, size_t ws_size,
                              hipStream_t stream) {
    const float* u        = (const float*)d_in[0];   // (B,)
    const float* states   = (const float*)d_in[1];   // (B,2)
    const float* centers  = (const float*)d_in[2];   // (32,)
    const float* logsig   = (const float*)d_in[3];   // (32,)
    const float* w        = (const float*)d_in[4];   // (32,)
    const float* b        = (const float*)d_in[5];   // (1,)

    int B = in_sizes[0];
    int n_pairs = B / 2;                             // 2,097,152
    int block = 256;                                 // == LUT_N
    int grid  = 2048;                                // grid-stride: 4 pairs/thread
    rk4_rbf_kernel<<<grid, block, 0, stream>>>(
        (const vfloat2*)u, (const vfloat4*)states,
        centers, logsig, w, b, (vfloat4*)d_out, n_pairs);
}

// Round 10
// 106.945 us; speedup vs baseline: 1.0349x; 1.0349x over previous
//
#include <hip/hip_runtime.h>

#define K_RBF   32
#define LUT_N   256           // points over [LUT_LO, LUT_HI]; intervals 0..254
#define LUT_LO  (-8.0f)
#define LUT_HI  (8.0f)
// h = 16/256 = 0.0625, inv_h = 16
#define LUT_INVH 16.0f

// Reference constants at float32 precision, exactly as jnp.float32(...)
#define DT_F      0.005f
#define M_INV_F   ((float)(1.0 / 95.452))
#define OFFST_F   (-3.2902f)
#define F_V_F     214.9261f
#define F_C_F     19.3607f

#if __has_builtin(__builtin_amdgcn_exp2f)
#define EXP2(x) __builtin_amdgcn_exp2f(x)
#else
#define EXP2(x) exp2f(x)
#endif

// Native clang vectors — accepted by __builtin_nontemporal_{load,store}.
typedef float vfloat4 __attribute__((ext_vector_type(4)));
typedef float vfloat2 __attribute__((ext_vector_type(2)));

// ---------------------------------------------------------------------------
// Single fused kernel (best measured configuration — R7, 105.65 us).
// Phase 1 (per block, ~0.15 us, hidden under streaming): build a 256-point
//   table of f(x) = b + sum_k w_k exp(-(s_k(x-c_k))^2) in LDS.
//   phi_k = exp2(q_k), q_k = A x^2 + B x + E with log2e folded in; 32 threads
//   first stage {A,B,E,w}, then each thread tabulates one grid point.
// Phase 2: grid-stride streaming, 2 elements/thread-iter, all streams
//   unit-stride (16B states, 8B u, 16B out per lane), nontemporal.
//   f,f' from LUT lerp (idx clamped to [0,254]); RK4 tail collapsed:
//     st1 = C6*k1*(6 - M_INV*(4h+DT)*(FVC+f'))
//     st0 = DT*x + C6*(4h+DT)*k1
//   (identical math to explicit Taylor-RK4; y0 dead; yd==k1, k3==k2.
//   LUT interp error ~2e-2 in f-space attenuates by C6*M_INV*4 ~ 3.5e-5
//   into the output -> ~1e-6, 500x under the 1.33e-3 threshold.)
// Falsified variants (all flat, R4-R9): 32B-stride 4-elem layout, block
// count 1024/2048/4096, NT vs plain stores, 8-deep load batching (MLP),
// paired-float2 LUT. Bytes are minimal (20 B/elem physical); residual vs
// the ~15-17 us 3-stream floor is dispatch ramp + mixed R/W efficiency.
// ---------------------------------------------------------------------------
__launch_bounds__(256)
__global__ void rk4_rbf_kernel(const vfloat2* __restrict__ u2,
                               const vfloat4* __restrict__ states4,
                               const float*  __restrict__ centers,
                               const float*  __restrict__ log_sigmas,
                               const float*  __restrict__ wts,
                               const float*  __restrict__ bptr,
                               vfloat4* __restrict__ out4,
                               int n_pairs) {
    __shared__ float4 P[K_RBF];     // {A, B, E, w} per RBF
    __shared__ float  F[LUT_N];     // f(x_i), 1 KB

    if (threadIdx.x < K_RBF) {
        const float LOG2E = 1.4426950408889634f;
        int k = threadIdx.x;
        float s  = __expf(log_sigmas[k]);
        float s2 = s * s;
        float c  = centers[k];
        P[k] = make_float4(-s2 * LOG2E,                 // A
                           2.0f * s2 * c * LOG2E,       // B
                           -s2 * c * c * LOG2E,         // E
                           wts[k]);                     // w
    }
    __syncthreads();

    {   // one LUT point per thread (blockDim.x == LUT_N == 256)
        const float H = (LUT_HI - LUT_LO) / (float)LUT_N;
        float xg = LUT_LO + (float)threadIdx.x * H;
        float fv = bptr[0];
#pragma unroll
        for (int k = 0; k < K_RBF; ++k) {
            float4 p = P[k];
            float q = fmaf(fmaf(p.x, xg, p.y), xg, p.z);
            fv = fmaf(p.w, EXP2(q), fv);
        }
        F[threadIdx.x] = fv;
    }
    __syncthreads();

    const float FVC = F_V_F + F_C_F;
    const float C6  = DT_F / 6.0f;
    const float C1  = 0.015f * M_INV_F;   // M_INV*(4h+DT)
    const float C2  = C6 * 0.015f;        // C6*(4h+DT)

    int stride = gridDim.x * blockDim.x;
    for (int i = blockIdx.x * blockDim.x + threadIdx.x; i < n_pairs; i += stride) {
        vfloat4 s  = __builtin_nontemporal_load(&states4[i]);  // y0a,y1a,y0b,y1b
        vfloat2 uu = __builtin_nontemporal_load(&u2[i]);

        float x[2]  = { s.y, s.w };     // y1 (y0 is dead)
        float uv[2] = { uu.x, uu.y };
        float o[4];
#pragma unroll
        for (int e = 0; e < 2; ++e) {
            float t   = (x[e] - LUT_LO) * LUT_INVH;
            t = fminf(fmaxf(t, 0.0f), (float)(LUT_N - 2) + 0.999f);
            int   idx = (int)t;
            float fr  = t - (float)idx;
            float f0  = F[idx];
            float df  = F[idx + 1] - f0;
            float f   = fmaf(fr, df, f0);           // f(x) incl. b
            float fp  = df * LUT_INVH;              // f'(x)

            float k1 = (uv[e] - FVC * x[e] - (OFFST_F + f)) * M_INV_F;
            float g  = 6.0f - C1 * (FVC + fp);
            o[2 * e]     = fmaf(C2, k1, DT_F * x[e]);   // st0
            o[2 * e + 1] = C6 * k1 * g;                 // st1
        }

        vfloat4 ov = { o[0], o[1], o[2], o[3] };
        __builtin_nontemporal_store(ov, &out4[i]);
    }
}

extern "C" void kernel_launch(void* const* d_in, const int* in_sizes, int n_in,
                              void* d_out, int out_size, void* d_ws, size_t ws_size,
                              hipStream_t stream) {
    const float* u        = (const float*)d_in[0];   // (B,)
    const float* states   = (const float*)d_in[1];   // (B,2)
    const float* centers  = (const float*)d_in[2];   // (32,)
    const float* logsig   = (const float*)d_in[3];   // (32,)
    const float* w        = (const float*)d_in[4];   // (32,)
    const float* b        = (const float*)d_in[5];   // (1,)

    int B = in_sizes[0];
    int n_pairs = B / 2;                             // 2,097,152
    int block = 256;                                 // == LUT_N
    int grid  = 2048;                                // grid-stride: 4 pairs/thread
    rk4_rbf_kernel<<<grid, block, 0, stream>>>(
        (const vfloat2*)u, (const vfloat4*)states,
        centers, logsig, w, b, (vfloat4*)d_out, n_pairs);
}